// Round 1
// baseline (1946.093 us; speedup 1.0000x reference)
//
#include <hip/hip_runtime.h>
#include <cmath>

constexpr int F1 = 128;  // input features
constexpr int H  = 64;   // hidden
constexpr int NC = 40;   // classes

// ---- setup: deg=1 (self loop), inverse sigmas ----
__global__ void setup_kernel(float* __restrict__ degf, int N,
                             const float* __restrict__ sig1, float* __restrict__ isg1,
                             const float* __restrict__ sig2, float* __restrict__ isg2) {
    int i = blockIdx.x * blockDim.x + threadIdx.x;
    if (i < N)  degf[i] = 1.0f;
    if (i < F1) isg1[i] = 1.0f / sig1[i];
    if (i < H)  isg2[i] = 1.0f / sig2[i];
}

__global__ void count_deg_kernel(const int* __restrict__ row, float* __restrict__ degf, int E) {
    int e = blockIdx.x * blockDim.x + threadIdx.x;
    if (e < E) atomicAdd(&degf[row[e]], 1.0f);
}

__global__ void dis_kernel(const float* __restrict__ degf, float* __restrict__ dis, int N) {
    int i = blockIdx.x * blockDim.x + threadIdx.x;
    if (i < N) dis[i] = rsqrtf(degf[i]);  // deg >= 1 always (self loop)
}

// ---- mask scatter: mask[row] += norm * ((x[col]-x[row])/sigma)^2, one wave per edge ----
template<int F>
__global__ void mask_scatter_kernel(const int* __restrict__ row, const int* __restrict__ col,
                                    const float* __restrict__ dis, const float* __restrict__ x,
                                    const float* __restrict__ isg, float* mask, int E) {
    int e = blockIdx.x * (blockDim.x >> 6) + (threadIdx.x >> 6);
    if (e >= E) return;
    int lane = threadIdx.x & 63;
    int r = row[e], c = col[e];
    float nrm = dis[r] * dis[c];
    const float* xr = x + (size_t)r * F;
    const float* xc = x + (size_t)c * F;
    float* mr = mask + (size_t)r * F;
#pragma unroll
    for (int k = 0; k < F / 64; ++k) {
        int f = lane + 64 * k;
        float d = (xc[f] - xr[f]) * isg[f];
        atomicAdd(&mr[f], nrm * d * d);
    }
}

// ---- xm = x * exp(-mask/deg) (safe in-place: xm may alias mask) ----
template<int F>
__global__ void apply_mask_kernel(const float* x, const float* mask,
                                  const float* __restrict__ degf, float* xm, size_t NF) {
    size_t idx = (size_t)blockIdx.x * blockDim.x + threadIdx.x;
    if (idx >= NF) return;
    size_t i = idx / F;
    xm[idx] = x[idx] * expf(-mask[idx] / degf[i]);
}

// ---- small dense GEMM: Y[N,O] = X[N,F] @ W[F,O]; W + X-rows staged in LDS ----
template<int F, int O, int R>
__global__ void gemm_kernel(const float* __restrict__ X, const float* __restrict__ W,
                            float* __restrict__ Y, int N) {
    static_assert(R * O <= 256, "tile too big");
    __shared__ float Ws[F * O];
    __shared__ float Xs[R][F];
    int tid = threadIdx.x;
    for (int i = tid; i < F * O; i += 256) Ws[i] = W[i];
    int row0 = blockIdx.x * R;
    for (int i = tid; i < R * F; i += 256) {
        int r = row0 + i / F;
        Xs[i / F][i % F] = (r < N) ? X[(size_t)r * F + (i % F)] : 0.0f;
    }
    __syncthreads();
    if (tid < R * O) {
        int r = tid / O, o = tid % O;
        int rr = row0 + r;
        if (rr < N) {
            float acc = 0.0f;
#pragma unroll
            for (int f = 0; f < F; ++f) acc = fmaf(Xs[r][f], Ws[f * O + o], acc);
            Y[(size_t)rr * O + o] = acc;
        }
    }
}

// ---- aggregation init with self-loop term: acc[i][o] = xw[i][o] * dis[i]^2 ----
template<int O>
__global__ void init_agg_kernel(const float* __restrict__ xw, const float* __restrict__ dis,
                                float* __restrict__ acc, int N) {
    size_t idx = (size_t)blockIdx.x * blockDim.x + threadIdx.x;
    if (idx >= (size_t)N * O) return;
    int i = (int)(idx / O);
    float d = dis[i];
    acc[idx] = xw[idx] * d * d;
}

// ---- aggregation scatter: acc[col] += norm * xw[row], one wave per edge ----
template<int O>
__global__ void agg_scatter_kernel(const int* __restrict__ row, const int* __restrict__ col,
                                   const float* __restrict__ dis, const float* __restrict__ xw,
                                   float* acc, int E) {
    int e = blockIdx.x * (blockDim.x >> 6) + (threadIdx.x >> 6);
    if (e >= E) return;
    int lane = threadIdx.x & 63;
    int r = row[e], c = col[e];
    float nrm = dis[r] * dis[c];
    if (O >= 64) {
#pragma unroll
        for (int k = 0; k < (O + 63) / 64; ++k) {
            int f = lane + 64 * k;
            if (f < O) atomicAdd(&acc[(size_t)c * O + f], nrm * xw[(size_t)r * O + f]);
        }
    } else {
        if (lane < O) atomicAdd(&acc[(size_t)c * O + lane], nrm * xw[(size_t)r * O + lane]);
    }
}

__global__ void bias_relu_kernel(const float* __restrict__ acc, const float* __restrict__ b,
                                 float* __restrict__ h, size_t NO) {
    size_t idx = (size_t)blockIdx.x * blockDim.x + threadIdx.x;
    if (idx >= NO) return;
    h[idx] = fmaxf(acc[idx] + b[idx & (H - 1)], 0.0f);
}

__global__ void bias_logsoftmax_kernel(float* out, const float* __restrict__ b, int N) {
    int i = blockIdx.x * blockDim.x + threadIdx.x;
    if (i >= N) return;
    float v[NC];
    float m = -INFINITY;
#pragma unroll
    for (int o = 0; o < NC; ++o) { v[o] = out[(size_t)i * NC + o] + b[o]; m = fmaxf(m, v[o]); }
    float s = 0.0f;
#pragma unroll
    for (int o = 0; o < NC; ++o) s += expf(v[o] - m);
    float ls = logf(s);
#pragma unroll
    for (int o = 0; o < NC; ++o) out[(size_t)i * NC + o] = v[o] - m - ls;
}

extern "C" void kernel_launch(void* const* d_in, const int* in_sizes, int n_in,
                              void* d_out, int out_size, void* d_ws, size_t ws_size,
                              hipStream_t stream) {
    const float* x    = (const float*)d_in[0];
    const int*   ei   = (const int*)  d_in[1];   // int32 on device (jax x64 disabled)
    const float* sig1 = (const float*)d_in[2];
    const float* W1   = (const float*)d_in[3];
    const float* b1   = (const float*)d_in[4];
    const float* sig2 = (const float*)d_in[5];
    const float* W2   = (const float*)d_in[6];
    const float* b2   = (const float*)d_in[7];
    float* out = (float*)d_out;

    const int N = in_sizes[0] / F1;
    const int E = in_sizes[1] / 2;
    const int* row = ei;
    const int* col = ei + E;

    float* p = (float*)d_ws;
    float* degf = p; p += N;
    float* dis  = p; p += N;
    float* isg1 = p; p += F1;
    float* isg2 = p; p += H;
    float* bufA = p; p += (size_t)N * F1;   // mask1 / xm1, later mask2 / xm2
    float* bufB = p; p += (size_t)N * H;    // xw1, later h1
    float* bufC = p; p += (size_t)N * H;    // agg1, later xw2

    const int B = 256;
    const int EPB = B / 64;                  // edges per block (wave per edge)
    dim3 eg((E + EPB - 1) / EPB);

    // graph prep
    hipMemsetAsync(bufA, 0, (size_t)N * F1 * sizeof(float), stream);   // mask1 = 0
    setup_kernel<<<(N + B - 1) / B, B, 0, stream>>>(degf, N, sig1, isg1, sig2, isg2);
    count_deg_kernel<<<(E + B - 1) / B, B, 0, stream>>>(row, degf, E);
    dis_kernel<<<(N + B - 1) / B, B, 0, stream>>>(degf, dis, N);

    // ---- layer 1 ----
    mask_scatter_kernel<F1><<<eg, B, 0, stream>>>(row, col, dis, x, isg1, bufA, E);
    apply_mask_kernel<F1><<<((size_t)N * F1 + B - 1) / B, B, 0, stream>>>(x, bufA, degf, bufA, (size_t)N * F1);
    gemm_kernel<F1, H, 4><<<(N + 3) / 4, B, 0, stream>>>(bufA, W1, bufB, N);
    init_agg_kernel<H><<<((size_t)N * H + B - 1) / B, B, 0, stream>>>(bufB, dis, bufC, N);
    agg_scatter_kernel<H><<<eg, B, 0, stream>>>(row, col, dis, bufB, bufC, E);
    bias_relu_kernel<<<((size_t)N * H + B - 1) / B, B, 0, stream>>>(bufC, b1, bufB, (size_t)N * H);

    // ---- layer 2 ----
    hipMemsetAsync(bufA, 0, (size_t)N * H * sizeof(float), stream);    // mask2 = 0
    mask_scatter_kernel<H><<<eg, B, 0, stream>>>(row, col, dis, bufB, isg2, bufA, E);
    apply_mask_kernel<H><<<((size_t)N * H + B - 1) / B, B, 0, stream>>>(bufB, bufA, degf, bufA, (size_t)N * H);
    gemm_kernel<H, NC, 6><<<(N + 5) / 6, B, 0, stream>>>(bufA, W2, bufC, N);
    init_agg_kernel<NC><<<((size_t)N * NC + B - 1) / B, B, 0, stream>>>(bufC, dis, out, N);
    agg_scatter_kernel<NC><<<eg, B, 0, stream>>>(row, col, dis, bufC, out, E);
    bias_logsoftmax_kernel<<<(N + B - 1) / B, B, 0, stream>>>(out, b2, N);
}

// Round 2
// 1554.548 us; speedup vs baseline: 1.2519x; 1.2519x over previous
//
#include <hip/hip_runtime.h>
#include <cmath>

constexpr int F1 = 128;  // input features
constexpr int H  = 64;   // hidden
constexpr int NC = 40;   // classes

// ---- inverse sigmas ----
__global__ void isg_kernel(const float* __restrict__ s1, float* __restrict__ i1,
                           const float* __restrict__ s2, float* __restrict__ i2) {
    int i = threadIdx.x;
    if (i < F1) i1[i] = 1.0f / s1[i];
    if (i < H)  i2[i] = 1.0f / s2[i];
}

// ---- degree histogram (out + in) ----
__global__ void count_kernel(const int* __restrict__ row, const int* __restrict__ col,
                             int* __restrict__ cntO, int* __restrict__ cntI, int E) {
    int e = blockIdx.x * blockDim.x + threadIdx.x;
    if (e < E) {
        atomicAdd(&cntO[row[e]], 1);
        atomicAdd(&cntI[col[e]], 1);
    }
}

// ---- single-block exclusive scan of both histograms -> rowptr; cnt arrays become cursors;
//      also dis = rsqrt(outdeg+1) ----
__global__ void scan_kernel(int* __restrict__ cntO, int* __restrict__ cntI,
                            int* __restrict__ rowptrO, int* __restrict__ rowptrI,
                            float* __restrict__ dis, int N) {
    __shared__ int sums[1024];
    int t = threadIdx.x;
    int chunk = (N + 1023) >> 10;
    int lo = min(t * chunk, N), hi = min(lo + chunk, N);

    // ---- pass O ----
    int s = 0;
    for (int i = lo; i < hi; ++i) s += cntO[i];
    sums[t] = s;
    __syncthreads();
    for (int off = 1; off < 1024; off <<= 1) {
        int v = (t >= off) ? sums[t - off] : 0;
        __syncthreads();
        sums[t] += v;
        __syncthreads();
    }
    int run = (t > 0) ? sums[t - 1] : 0;
    int totalO = sums[1023];
    for (int i = lo; i < hi; ++i) {
        int cv = cntO[i];
        rowptrO[i] = run;
        cntO[i] = run;                       // becomes cursor
        dis[i] = rsqrtf((float)(cv + 1));    // deg includes self-loop
        run += cv;
    }
    if (t == 0) rowptrO[N] = totalO;
    __syncthreads();

    // ---- pass I ----
    s = 0;
    for (int i = lo; i < hi; ++i) s += cntI[i];
    sums[t] = s;
    __syncthreads();
    for (int off = 1; off < 1024; off <<= 1) {
        int v = (t >= off) ? sums[t - off] : 0;
        __syncthreads();
        sums[t] += v;
        __syncthreads();
    }
    run = (t > 0) ? sums[t - 1] : 0;
    int totalI = sums[1023];
    for (int i = lo; i < hi; ++i) {
        int cv = cntI[i];
        rowptrI[i] = run;
        cntI[i] = run;                       // becomes cursor
        run += cv;
    }
    if (t == 0) rowptrI[N] = totalI;
}

// ---- fill adjacency via cursor scatter ----
__global__ void build_kernel(const int* __restrict__ row, const int* __restrict__ col,
                             int* __restrict__ curO, int* __restrict__ curI,
                             int* __restrict__ adjO, int* __restrict__ adjI, int E) {
    int e = blockIdx.x * blockDim.x + threadIdx.x;
    if (e >= E) return;
    int r = row[e], c = col[e];
    adjO[atomicAdd(&curO[r], 1)] = c;
    adjI[atomicAdd(&curI[c], 1)] = r;
}

// ---- fused: per-wave mask gather + apply -> LDS X tile -> dense GEMM  Y = xm @ W ----
// one wave per node row; R rows (=waves) per block
template<int F, int O, int R>
__global__ void fused_mask_gemm_kernel(const int* __restrict__ rowptr, const int* __restrict__ adj,
                                       const float* __restrict__ dis, const float* __restrict__ x,
                                       const float* __restrict__ isg, const float* __restrict__ W,
                                       float* __restrict__ Y, int N) {
    constexpr int VE = F / 64;
    constexpr int NT = R * 64;
    __shared__ float Ws[F * O];
    __shared__ float Xs[R][F];
    int tid = threadIdx.x;
    for (int i = tid; i < F * O; i += NT) Ws[i] = W[i];

    int w = tid >> 6, lane = tid & 63;
    int r = blockIdx.x * R + w;
    if (r < N) {
        int beg = rowptr[r], end = rowptr[r + 1];
        float dr = dis[r];
        float inv_deg = 1.0f / (float)(end - beg + 1);
        float xr[VE], sg[VE], acc[VE];
#pragma unroll
        for (int k = 0; k < VE; ++k) {
            xr[k] = x[(size_t)r * F + lane + 64 * k];
            sg[k] = isg[lane + 64 * k];
            acc[k] = 0.0f;
        }
        for (int base = beg; base < end; base += 64) {
            int nn = min(64, end - base);
            int cl = 0; float dl = 0.0f;
            if (base + lane < end) { cl = adj[base + lane]; dl = dis[cl]; }
            for (int i = 0; i < nn; ++i) {
                int c = __shfl(cl, i);
                float nrm = dr * __shfl(dl, i);
                const float* xc = x + (size_t)c * F;
#pragma unroll
                for (int k = 0; k < VE; ++k) {
                    float d = (xc[lane + 64 * k] - xr[k]) * sg[k];
                    acc[k] = fmaf(nrm * d, d, acc[k]);
                }
            }
        }
#pragma unroll
        for (int k = 0; k < VE; ++k)
            Xs[w][lane + 64 * k] = xr[k] * expf(-acc[k] * inv_deg);
    } else {
#pragma unroll
        for (int k = 0; k < VE; ++k) Xs[w][lane + 64 * k] = 0.0f;
    }
    __syncthreads();

    int row0 = blockIdx.x * R;
    for (int idx = tid; idx < R * O; idx += NT) {
        int rr = idx / O, o = idx % O;
        if (row0 + rr < N) {
            float acc = 0.0f;
#pragma unroll
            for (int f = 0; f < F; ++f) acc = fmaf(Xs[rr][f], Ws[f * O + o], acc);
            Y[(size_t)(row0 + rr) * O + o] = acc;
        }
    }
}

// ---- aggregation gather: out[c] = sum_in-edges dis[r]*dis[c]*xw[r] + dis[c]^2*xw[c], + epilogue
// MODE 0: bias+relu   MODE 1: bias+log_softmax (over O lanes)
template<int O, int MODE>
__global__ void agg_gather_kernel(const int* __restrict__ rowptr, const int* __restrict__ adj,
                                  const float* __restrict__ dis, const float* __restrict__ xw,
                                  const float* __restrict__ bias, float* __restrict__ out, int N) {
    int c = blockIdx.x * (blockDim.x >> 6) + (threadIdx.x >> 6);
    if (c >= N) return;
    int lane = threadIdx.x & 63;
    int beg = rowptr[c], end = rowptr[c + 1];
    float dc = dis[c];
    float acc = 0.0f;
    if (lane < O) acc = dc * dc * xw[(size_t)c * O + lane];
    for (int base = beg; base < end; base += 64) {
        int nn = min(64, end - base);
        int rl = 0; float dl = 0.0f;
        if (base + lane < end) { rl = adj[base + lane]; dl = dis[rl]; }
        for (int i = 0; i < nn; ++i) {
            int r = __shfl(rl, i);
            float nrm = dc * __shfl(dl, i);
            if (lane < O) acc = fmaf(nrm, xw[(size_t)r * O + lane], acc);
        }
    }
    if (MODE == 0) {
        if (lane < O) out[(size_t)c * O + lane] = fmaxf(acc + bias[lane], 0.0f);
    } else {
        float v = (lane < O) ? acc + bias[lane] : -INFINITY;
        float m = v;
        for (int off = 32; off > 0; off >>= 1) m = fmaxf(m, __shfl_xor(m, off));
        float s = (lane < O) ? expf(v - m) : 0.0f;
        for (int off = 32; off > 0; off >>= 1) s += __shfl_xor(s, off);
        float ls = logf(s);
        if (lane < O) out[(size_t)c * O + lane] = v - m - ls;
    }
}

extern "C" void kernel_launch(void* const* d_in, const int* in_sizes, int n_in,
                              void* d_out, int out_size, void* d_ws, size_t ws_size,
                              hipStream_t stream) {
    const float* x    = (const float*)d_in[0];
    const int*   ei   = (const int*)  d_in[1];
    const float* sig1 = (const float*)d_in[2];
    const float* W1   = (const float*)d_in[3];
    const float* b1   = (const float*)d_in[4];
    const float* sig2 = (const float*)d_in[5];
    const float* W2   = (const float*)d_in[6];
    const float* b2   = (const float*)d_in[7];
    float* out = (float*)d_out;

    const int N = in_sizes[0] / F1;
    const int E = in_sizes[1] / 2;
    const int* row = ei;
    const int* col = ei + E;

    char* w = (char*)d_ws;
    auto alloc = [&](size_t bytes) { void* q = w; w += (bytes + 255) & ~255ull; return q; };
    int*   cntO    = (int*)  alloc((size_t)2 * N * 4);   // cntO,cntI adjacent (one memset)
    int*   cntI    = cntO + N;
    int*   rowptrO = (int*)  alloc((size_t)(N + 1) * 4);
    int*   rowptrI = (int*)  alloc((size_t)(N + 1) * 4);
    int*   adjO    = (int*)  alloc((size_t)E * 4);
    int*   adjI    = (int*)  alloc((size_t)E * 4);
    float* dis     = (float*)alloc((size_t)N * 4);
    float* isg1    = (float*)alloc(F1 * 4);
    float* isg2    = (float*)alloc(H * 4);
    float* bufXW   = (float*)alloc((size_t)N * H * 4);   // xw1
    float* bufH    = (float*)alloc((size_t)N * H * 4);   // h1
    float* bufXW2  = (float*)alloc((size_t)N * NC * 4);  // xw2

    const int B = 256;
    dim3 ng((N + 3) / 4);  // 4 waves (nodes) per block

    // ---- graph build ----
    hipMemsetAsync(cntO, 0, (size_t)2 * N * 4, stream);
    isg_kernel<<<1, 128, 0, stream>>>(sig1, isg1, sig2, isg2);
    count_kernel<<<(E + B - 1) / B, B, 0, stream>>>(row, col, cntO, cntI, E);
    scan_kernel<<<1, 1024, 0, stream>>>(cntO, cntI, rowptrO, rowptrI, dis, N);
    build_kernel<<<(E + B - 1) / B, B, 0, stream>>>(row, col, cntO, cntI, adjO, adjI, E);

    // ---- layer 1 ----
    fused_mask_gemm_kernel<F1, H, 4><<<ng, B, 0, stream>>>(rowptrO, adjO, dis, x, isg1, W1, bufXW, N);
    agg_gather_kernel<H, 0><<<ng, B, 0, stream>>>(rowptrI, adjI, dis, bufXW, b1, bufH, N);

    // ---- layer 2 ----
    fused_mask_gemm_kernel<H, NC, 4><<<ng, B, 0, stream>>>(rowptrO, adjO, dis, bufH, isg2, W2, bufXW2, N);
    agg_gather_kernel<NC, 1><<<ng, B, 0, stream>>>(rowptrI, adjI, dis, bufXW2, b2, out, N);
}

// Round 3
// 1059.691 us; speedup vs baseline: 1.8365x; 1.4670x over previous
//
#include <hip/hip_runtime.h>
#include <cmath>

constexpr int F1 = 128;  // input features
constexpr int H  = 64;   // hidden
constexpr int NC = 40;   // classes

constexpr int SCAN_TPB = 256;
constexpr int SCAN_IPT = 8;
constexpr int SCAN_EPB = SCAN_TPB * SCAN_IPT;  // 2048 elements per block

// ---- inverse sigmas ----
__global__ void isg_kernel(const float* __restrict__ s1, float* __restrict__ i1,
                           const float* __restrict__ s2, float* __restrict__ i2) {
    int i = threadIdx.x;
    if (i < F1) i1[i] = 1.0f / s1[i];
    if (i < H)  i2[i] = 1.0f / s2[i];
}

// ---- degree histogram (out + in) ----
__global__ void count_kernel(const int* __restrict__ row, const int* __restrict__ col,
                             int* __restrict__ cntO, int* __restrict__ cntI, int E) {
    int e = blockIdx.x * blockDim.x + threadIdx.x;
    if (e < E) {
        atomicAdd(&cntO[row[e]], 1);
        atomicAdd(&cntI[col[e]], 1);
    }
}

// ---- multi-block exclusive scan over cnt[0..M) (M = 2N: cntO|cntI contiguous) ----
__global__ void scan_partial_kernel(const int* __restrict__ cnt, int* __restrict__ bsum, int M) {
    __shared__ int red[SCAN_TPB];
    int t = threadIdx.x;
    int i0 = blockIdx.x * SCAN_EPB + t * SCAN_IPT;
    int s = 0;
#pragma unroll
    for (int k = 0; k < SCAN_IPT; ++k) {
        int i = i0 + k;
        if (i < M) s += cnt[i];
    }
    red[t] = s;
    __syncthreads();
    for (int off = SCAN_TPB / 2; off > 0; off >>= 1) {
        if (t < off) red[t] += red[t + off];
        __syncthreads();
    }
    if (t == 0) bsum[blockIdx.x] = red[0];
}

__global__ void scan_offsets_kernel(int* __restrict__ bsum, int nb,
                                    int* __restrict__ rowptrO, int* __restrict__ rowptrI,
                                    int N, int E) {
    __shared__ int sh[1024];
    int t = threadIdx.x;
    sh[t] = (t < nb) ? bsum[t] : 0;
    __syncthreads();
    for (int off = 1; off < 1024; off <<= 1) {
        int v = (t >= off) ? sh[t - off] : 0;
        __syncthreads();
        sh[t] += v;
        __syncthreads();
    }
    if (t < nb) bsum[t] = (t > 0) ? sh[t - 1] : 0;  // exclusive block offsets
    if (t == 0) { rowptrO[N] = E; rowptrI[N] = E; }
}

__global__ void scan_final_kernel(int* __restrict__ cntO, int* __restrict__ cntI,
                                  const int* __restrict__ bsum,
                                  int* __restrict__ rowptrO, int* __restrict__ rowptrI,
                                  float* __restrict__ dis, int N, int E) {
    __shared__ int sh[SCAN_TPB];
    int t = threadIdx.x;
    int M = 2 * N;
    const int* cnt = cntO;  // cntI == cntO + N (contiguous)
    int i0 = blockIdx.x * SCAN_EPB + t * SCAN_IPT;
    int cv[SCAN_IPT], pre[SCAN_IPT];
    int run = 0;
#pragma unroll
    for (int k = 0; k < SCAN_IPT; ++k) {
        int i = i0 + k;
        cv[k] = (i < M) ? cnt[i] : 0;
        pre[k] = run;
        run += cv[k];
    }
    sh[t] = run;
    __syncthreads();
    for (int off = 1; off < SCAN_TPB; off <<= 1) {
        int v = (t >= off) ? sh[t - off] : 0;
        __syncthreads();
        sh[t] += v;
        __syncthreads();
    }
    int toff = ((t > 0) ? sh[t - 1] : 0) + bsum[blockIdx.x];
#pragma unroll
    for (int k = 0; k < SCAN_IPT; ++k) {
        int i = i0 + k;
        if (i < M) {
            int val = toff + pre[k];
            if (i < N) {
                rowptrO[i] = val;
                cntO[i] = val;                         // cursor
                dis[i] = rsqrtf((float)(cv[k] + 1));   // deg includes self-loop
            } else {
                rowptrI[i - N] = val - E;
                cntI[i - N] = val - E;                 // cursor
            }
        }
    }
}

// ---- fill adjacency via cursor scatter ----
__global__ void build_kernel(const int* __restrict__ row, const int* __restrict__ col,
                             int* __restrict__ curO, int* __restrict__ curI,
                             int* __restrict__ adjO, int* __restrict__ adjI, int E) {
    int e = blockIdx.x * blockDim.x + threadIdx.x;
    if (e >= E) return;
    int r = row[e], c = col[e];
    adjO[atomicAdd(&curO[r], 1)] = c;
    adjI[atomicAdd(&curI[c], 1)] = r;
}

// ---- fused: per-wave mask gather + apply -> LDS X tile -> dense GEMM  Y = xm @ W ----
// one wave per node row; R rows (=waves) per block
template<int F, int O, int R>
__global__ void fused_mask_gemm_kernel(const int* __restrict__ rowptr, const int* __restrict__ adj,
                                       const float* __restrict__ dis, const float* __restrict__ x,
                                       const float* __restrict__ isg, const float* __restrict__ W,
                                       float* __restrict__ Y, int N) {
    constexpr int VE = F / 64;
    constexpr int NT = R * 64;
    __shared__ float Ws[F * O];
    __shared__ float Xs[R][F];
    int tid = threadIdx.x;
    for (int i = tid; i < F * O; i += NT) Ws[i] = W[i];

    int w = tid >> 6, lane = tid & 63;
    int r = blockIdx.x * R + w;
    if (r < N) {
        int beg = rowptr[r], end = rowptr[r + 1];
        float dr = dis[r];
        float inv_deg = 1.0f / (float)(end - beg + 1);
        float xr[VE], sg[VE], acc[VE];
#pragma unroll
        for (int k = 0; k < VE; ++k) {
            xr[k] = x[(size_t)r * F + lane + 64 * k];
            sg[k] = isg[lane + 64 * k];
            acc[k] = 0.0f;
        }
        for (int base = beg; base < end; base += 64) {
            int nn = min(64, end - base);
            int cl = 0; float dl = 0.0f;
            if (base + lane < end) { cl = adj[base + lane]; dl = dis[cl]; }
            for (int i = 0; i < nn; ++i) {
                int c = __shfl(cl, i);
                float nrm = dr * __shfl(dl, i);
                const float* xc = x + (size_t)c * F;
#pragma unroll
                for (int k = 0; k < VE; ++k) {
                    float d = (xc[lane + 64 * k] - xr[k]) * sg[k];
                    acc[k] = fmaf(nrm * d, d, acc[k]);
                }
            }
        }
#pragma unroll
        for (int k = 0; k < VE; ++k)
            Xs[w][lane + 64 * k] = xr[k] * expf(-acc[k] * inv_deg);
    } else {
#pragma unroll
        for (int k = 0; k < VE; ++k) Xs[w][lane + 64 * k] = 0.0f;
    }
    __syncthreads();

    int row0 = blockIdx.x * R;
    for (int idx = tid; idx < R * O; idx += NT) {
        int rr = idx / O, o = idx % O;
        if (row0 + rr < N) {
            float acc = 0.0f;
#pragma unroll
            for (int f = 0; f < F; ++f) acc = fmaf(Xs[rr][f], Ws[f * O + o], acc);
            Y[(size_t)(row0 + rr) * O + o] = acc;
        }
    }
}

// ---- aggregation gather: out[c] = sum_in-edges dis[r]*dis[c]*xw[r] + dis[c]^2*xw[c], + epilogue
// MODE 0: bias+relu   MODE 1: bias+log_softmax (over O lanes)
template<int O, int MODE>
__global__ void agg_gather_kernel(const int* __restrict__ rowptr, const int* __restrict__ adj,
                                  const float* __restrict__ dis, const float* __restrict__ xw,
                                  const float* __restrict__ bias, float* __restrict__ out, int N) {
    int c = blockIdx.x * (blockDim.x >> 6) + (threadIdx.x >> 6);
    if (c >= N) return;
    int lane = threadIdx.x & 63;
    int beg = rowptr[c], end = rowptr[c + 1];
    float dc = dis[c];
    float acc = 0.0f;
    if (lane < O) acc = dc * dc * xw[(size_t)c * O + lane];
    for (int base = beg; base < end; base += 64) {
        int nn = min(64, end - base);
        int rl = 0; float dl = 0.0f;
        if (base + lane < end) { rl = adj[base + lane]; dl = dis[rl]; }
        for (int i = 0; i < nn; ++i) {
            int r = __shfl(rl, i);
            float nrm = dc * __shfl(dl, i);
            if (lane < O) acc = fmaf(nrm, xw[(size_t)r * O + lane], acc);
        }
    }
    if (MODE == 0) {
        if (lane < O) out[(size_t)c * O + lane] = fmaxf(acc + bias[lane], 0.0f);
    } else {
        float v = (lane < O) ? acc + bias[lane] : -INFINITY;
        float m = v;
        for (int off = 32; off > 0; off >>= 1) m = fmaxf(m, __shfl_xor(m, off));
        float s = (lane < O) ? expf(v - m) : 0.0f;
        for (int off = 32; off > 0; off >>= 1) s += __shfl_xor(s, off);
        float ls = logf(s);
        if (lane < O) out[(size_t)c * O + lane] = v - m - ls;
    }
}

extern "C" void kernel_launch(void* const* d_in, const int* in_sizes, int n_in,
                              void* d_out, int out_size, void* d_ws, size_t ws_size,
                              hipStream_t stream) {
    const float* x    = (const float*)d_in[0];
    const int*   ei   = (const int*)  d_in[1];
    const float* sig1 = (const float*)d_in[2];
    const float* W1   = (const float*)d_in[3];
    const float* b1   = (const float*)d_in[4];
    const float* sig2 = (const float*)d_in[5];
    const float* W2   = (const float*)d_in[6];
    const float* b2   = (const float*)d_in[7];
    float* out = (float*)d_out;

    const int N = in_sizes[0] / F1;
    const int E = in_sizes[1] / 2;
    const int* row = ei;
    const int* col = ei + E;

    char* w = (char*)d_ws;
    auto alloc = [&](size_t bytes) { void* q = w; w += (bytes + 255) & ~255ull; return q; };
    int*   cntO    = (int*)  alloc((size_t)2 * N * 4);   // cntO,cntI adjacent (one memset, one scan)
    int*   cntI    = cntO + N;
    int*   rowptrO = (int*)  alloc((size_t)(N + 1) * 4);
    int*   rowptrI = (int*)  alloc((size_t)(N + 1) * 4);
    int*   adjO    = (int*)  alloc((size_t)E * 4);
    int*   adjI    = (int*)  alloc((size_t)E * 4);
    float* dis     = (float*)alloc((size_t)N * 4);
    float* isg1    = (float*)alloc(F1 * 4);
    float* isg2    = (float*)alloc(H * 4);
    int*   bsum    = (int*)  alloc(1024 * 4);
    float* bufXW   = (float*)alloc((size_t)N * H * 4);   // xw1
    float* bufH    = (float*)alloc((size_t)N * H * 4);   // h1
    float* bufXW2  = (float*)alloc((size_t)N * NC * 4);  // xw2

    const int B = 256;
    dim3 ng((N + 3) / 4);  // 4 waves (nodes) per block
    const int M = 2 * N;
    const int nb = (M + SCAN_EPB - 1) / SCAN_EPB;        // 98 blocks for N=100k (must be <=1024)

    // ---- graph build ----
    hipMemsetAsync(cntO, 0, (size_t)2 * N * 4, stream);
    isg_kernel<<<1, 128, 0, stream>>>(sig1, isg1, sig2, isg2);
    count_kernel<<<(E + B - 1) / B, B, 0, stream>>>(row, col, cntO, cntI, E);
    scan_partial_kernel<<<nb, SCAN_TPB, 0, stream>>>(cntO, bsum, M);
    scan_offsets_kernel<<<1, 1024, 0, stream>>>(bsum, nb, rowptrO, rowptrI, N, E);
    scan_final_kernel<<<nb, SCAN_TPB, 0, stream>>>(cntO, cntI, bsum, rowptrO, rowptrI, dis, N, E);
    build_kernel<<<(E + B - 1) / B, B, 0, stream>>>(row, col, cntO, cntI, adjO, adjI, E);

    // ---- layer 1 ----
    fused_mask_gemm_kernel<F1, H, 4><<<ng, B, 0, stream>>>(rowptrO, adjO, dis, x, isg1, W1, bufXW, N);
    agg_gather_kernel<H, 0><<<ng, B, 0, stream>>>(rowptrI, adjI, dis, bufXW, b1, bufH, N);

    // ---- layer 2 ----
    fused_mask_gemm_kernel<H, NC, 4><<<ng, B, 0, stream>>>(rowptrO, adjO, dis, bufH, isg2, W2, bufXW2, N);
    agg_gather_kernel<NC, 1><<<ng, B, 0, stream>>>(rowptrI, adjI, dis, bufXW2, b2, out, N);
}

// Round 5
// 718.631 us; speedup vs baseline: 2.7081x; 1.4746x over previous
//
#include <hip/hip_runtime.h>
#include <cmath>

constexpr int F1 = 128;  // input features
constexpr int H  = 64;   // hidden
constexpr int NC = 40;   // classes
constexpr int NXCD = 8;

constexpr int SCAN_TPB = 256;
constexpr int SCAN_IPT = 8;
constexpr int SCAN_EPB = SCAN_TPB * SCAN_IPT;  // 2048 elements per block

// ---- inverse sigmas ----
__global__ void isg_kernel(const float* __restrict__ s1, float* __restrict__ i1,
                           const float* __restrict__ s2, float* __restrict__ i2) {
    int i = threadIdx.x;
    if (i < F1) i1[i] = 1.0f / s1[i];
    if (i < H)  i2[i] = 1.0f / s2[i];
}

// ---- XCD-partitioned degree histogram: blocks with bid%8==p only touch nodes in partition p
//      (cnt lines stay XCD-private under round-robin dispatch; correctness independent of mapping) ----
__global__ void count8_kernel(const int* __restrict__ row, const int* __restrict__ col,
                              int* __restrict__ cntO, int* __restrict__ cntI,
                              int E, int chunk, int stride) {
    int p = blockIdx.x & (NXCD - 1);
    int gid = blockIdx.x >> 3;
    unsigned lo = (unsigned)(p * chunk);
    for (int e = gid * blockDim.x + threadIdx.x; e < E; e += stride) {
        int r = row[e], c = col[e];
        if ((unsigned)r - lo < (unsigned)chunk) atomicAdd(&cntO[r], 1);
        if ((unsigned)c - lo < (unsigned)chunk) atomicAdd(&cntI[c], 1);
    }
}

// ---- multi-block exclusive scan over cnt[0..M) (M = 2N: cntO|cntI contiguous) ----
__global__ void scan_partial_kernel(const int* __restrict__ cnt, int* __restrict__ bsum, int M) {
    __shared__ int red[SCAN_TPB];
    int t = threadIdx.x;
    int i0 = blockIdx.x * SCAN_EPB + t * SCAN_IPT;
    int s = 0;
#pragma unroll
    for (int k = 0; k < SCAN_IPT; ++k) {
        int i = i0 + k;
        if (i < M) s += cnt[i];
    }
    red[t] = s;
    __syncthreads();
    for (int off = SCAN_TPB / 2; off > 0; off >>= 1) {
        if (t < off) red[t] += red[t + off];
        __syncthreads();
    }
    if (t == 0) bsum[blockIdx.x] = red[0];
}

__global__ void scan_offsets_kernel(int* __restrict__ bsum, int nb,
                                    int* __restrict__ rowptrO, int* __restrict__ rowptrI,
                                    int N, int E) {
    __shared__ int sh[1024];
    int t = threadIdx.x;
    sh[t] = (t < nb) ? bsum[t] : 0;
    __syncthreads();
    for (int off = 1; off < 1024; off <<= 1) {
        int v = (t >= off) ? sh[t - off] : 0;
        __syncthreads();
        sh[t] += v;
        __syncthreads();
    }
    if (t < nb) bsum[t] = (t > 0) ? sh[t - 1] : 0;  // exclusive block offsets
    if (t == 0) { rowptrO[N] = E; rowptrI[N] = E; }
}

__global__ void scan_final_kernel(int* __restrict__ cntO, int* __restrict__ cntI,
                                  const int* __restrict__ bsum,
                                  int* __restrict__ rowptrO, int* __restrict__ rowptrI,
                                  float* __restrict__ dis, int N, int E) {
    __shared__ int sh[SCAN_TPB];
    int t = threadIdx.x;
    int M = 2 * N;
    const int* cnt = cntO;  // cntI == cntO + N (contiguous)
    int i0 = blockIdx.x * SCAN_EPB + t * SCAN_IPT;
    int cv[SCAN_IPT], pre[SCAN_IPT];
    int run = 0;
#pragma unroll
    for (int k = 0; k < SCAN_IPT; ++k) {
        int i = i0 + k;
        cv[k] = (i < M) ? cnt[i] : 0;
        pre[k] = run;
        run += cv[k];
    }
    sh[t] = run;
    __syncthreads();
    for (int off = 1; off < SCAN_TPB; off <<= 1) {
        int v = (t >= off) ? sh[t - off] : 0;
        __syncthreads();
        sh[t] += v;
        __syncthreads();
    }
    int toff = ((t > 0) ? sh[t - 1] : 0) + bsum[blockIdx.x];
#pragma unroll
    for (int k = 0; k < SCAN_IPT; ++k) {
        int i = i0 + k;
        if (i < M) {
            int val = toff + pre[k];
            if (i < N) {
                rowptrO[i] = val;
                cntO[i] = val;                         // cursor
                dis[i] = rsqrtf((float)(cv[k] + 1));   // deg includes self-loop
            } else {
                rowptrI[i - N] = val - E;
                cntI[i - N] = val - E;                 // cursor
            }
        }
    }
}

// ---- XCD-partitioned adjacency fill (adj/cursor regions XCD-private per partition) ----
__global__ void build8_kernel(const int* __restrict__ row, const int* __restrict__ col,
                              int* __restrict__ curO, int* __restrict__ curI,
                              int* __restrict__ adjO, int* __restrict__ adjI,
                              int E, int chunk, int stride) {
    int p = blockIdx.x & (NXCD - 1);
    int gid = blockIdx.x >> 3;
    unsigned lo = (unsigned)(p * chunk);
    for (int e = gid * blockDim.x + threadIdx.x; e < E; e += stride) {
        int r = row[e], c = col[e];
        if ((unsigned)r - lo < (unsigned)chunk) adjO[atomicAdd(&curO[r], 1)] = c;
        if ((unsigned)c - lo < (unsigned)chunk) adjI[atomicAdd(&curI[c], 1)] = r;
    }
}

// ---- fused: per-wave mask gather + apply -> LDS X tile -> dense GEMM  Y = xm @ W ----
// one wave per node row; R rows (=waves) per block; float4 gathers, 64/(F/4) neighbors/iter
template<int F, int O, int R>
__global__ void fused_mask_gemm_kernel(const int* __restrict__ rowptr, const int* __restrict__ adj,
                                       const float* __restrict__ dis, const float* __restrict__ x,
                                       const float* __restrict__ isg, const float* __restrict__ W,
                                       float* __restrict__ Y, int N) {
    constexpr int NT = R * 64;
    constexpr int G = F / 4;        // lanes covering one row with float4
    constexpr int NPI = 64 / G;     // neighbors per wave-iteration
    __shared__ __align__(16) float Ws[F * O];
    __shared__ __align__(16) float Xs[R][F];
    int tid = threadIdx.x;
    for (int i = tid; i < F * O; i += NT) Ws[i] = W[i];

    int w = tid >> 6, lane = tid & 63;
    int h = lane / G;               // neighbor slot within iteration
    int j = lane % G;               // float4 index within row
    int r = blockIdx.x * R + w;
    if (r < N) {
        int beg = rowptr[r], end = rowptr[r + 1];
        float dr = dis[r];
        float inv_deg = 1.0f / (float)(end - beg + 1);
        float4 xr = *(const float4*)&x[(size_t)r * F + 4 * j];
        float4 sg = *(const float4*)&isg[4 * j];
        float4 acc = {0.f, 0.f, 0.f, 0.f};
        for (int base = beg; base < end; base += 64) {
            int nn = min(64, end - base);
            int cl = 0; float dl = 0.0f;
            if (base + lane < end) { cl = adj[base + lane]; dl = dis[cl]; }
            for (int t = 0; t < nn; t += NPI) {
                int i = t + h;
                bool valid = i < nn;
                int ii = valid ? i : 0;
                int c = __shfl(cl, ii);
                float nrm = valid ? dr * __shfl(dl, ii) : 0.0f;
                float4 xc = *(const float4*)&x[(size_t)c * F + 4 * j];
                float d0 = (xc.x - xr.x) * sg.x;
                float d1 = (xc.y - xr.y) * sg.y;
                float d2 = (xc.z - xr.z) * sg.z;
                float d3 = (xc.w - xr.w) * sg.w;
                acc.x = fmaf(nrm * d0, d0, acc.x);
                acc.y = fmaf(nrm * d1, d1, acc.y);
                acc.z = fmaf(nrm * d2, d2, acc.z);
                acc.w = fmaf(nrm * d3, d3, acc.w);
            }
        }
#pragma unroll
        for (int off = G; off < 64; off <<= 1) {
            acc.x += __shfl_xor(acc.x, off);
            acc.y += __shfl_xor(acc.y, off);
            acc.z += __shfl_xor(acc.z, off);
            acc.w += __shfl_xor(acc.w, off);
        }
        if (h == 0) {
            float4 xm;
            xm.x = xr.x * expf(-acc.x * inv_deg);
            xm.y = xr.y * expf(-acc.y * inv_deg);
            xm.z = xr.z * expf(-acc.z * inv_deg);
            xm.w = xr.w * expf(-acc.w * inv_deg);
            *(float4*)&Xs[w][4 * j] = xm;
        }
    } else {
        if (h == 0) *(float4*)&Xs[w][4 * j] = {0.f, 0.f, 0.f, 0.f};
    }
    __syncthreads();

    int row0 = blockIdx.x * R;
    for (int idx = tid; idx < R * O; idx += NT) {
        int rr = idx / O, o = idx % O;
        if (row0 + rr < N) {
            float acc = 0.0f;
#pragma unroll
            for (int f = 0; f < F; ++f) acc = fmaf(Xs[rr][f], Ws[f * O + o], acc);
            Y[(size_t)(row0 + rr) * O + o] = acc;
        }
    }
}

// ---- aggregation gather: out[c] = sum_in-edges dis[r]*dis[c]*xw[r] + dis[c]^2*xw[c], + epilogue
// float2 loads, 2 neighbors per iteration (half-wave split). MODE 0: bias+relu  MODE 1: bias+log_softmax
template<int O, int MODE>
__global__ void agg_gather_kernel(const int* __restrict__ rowptr, const int* __restrict__ adj,
                                  const float* __restrict__ dis, const float* __restrict__ xw,
                                  const float* __restrict__ bias, float* __restrict__ out, int N) {
    int c = blockIdx.x * (blockDim.x >> 6) + (threadIdx.x >> 6);
    if (c >= N) return;
    int lane = threadIdx.x & 63;
    int j = lane & 31, h = lane >> 5;
    bool active = (2 * j < O);
    int beg = rowptr[c], end = rowptr[c + 1];
    float dc = dis[c];
    float ax = 0.f, ay = 0.f;
    // self-loop term: ONLY in the h==0 half (halves are combined by shfl_xor(32) below;
    // R4 bug was adding it in both halves -> double count)
    if (h == 0 && active) {
        float2 v = *(const float2*)&xw[(size_t)c * O + 2 * j];
        ax = dc * dc * v.x; ay = dc * dc * v.y;
    }
    for (int base = beg; base < end; base += 64) {
        int nn = min(64, end - base);
        int rl = 0; float dl = 0.0f;
        if (base + lane < end) { rl = adj[base + lane]; dl = dis[rl]; }
        for (int t = 0; t < nn; t += 2) {
            int i = t + h;
            bool valid = i < nn;
            int ii = valid ? i : 0;
            int rr = __shfl(rl, ii);
            float nrm = valid ? dc * __shfl(dl, ii) : 0.0f;
            if (active) {
                float2 v = *(const float2*)&xw[(size_t)rr * O + 2 * j];
                ax = fmaf(nrm, v.x, ax);
                ay = fmaf(nrm, v.y, ay);
            }
        }
    }
    ax += __shfl_xor(ax, 32);
    ay += __shfl_xor(ay, 32);
    if (MODE == 0) {
        if (h == 0 && active) {
            float2 bb = *(const float2*)&bias[2 * j];
            float2 o2;
            o2.x = fmaxf(ax + bb.x, 0.0f);
            o2.y = fmaxf(ay + bb.y, 0.0f);
            *(float2*)&out[(size_t)c * O + 2 * j] = o2;
        }
    } else {
        float vx = -INFINITY, vy = -INFINITY;
        if (active) {
            float2 bb = *(const float2*)&bias[2 * j];
            vx = ax + bb.x; vy = ay + bb.y;
        }
        float m = fmaxf(vx, vy);
#pragma unroll
        for (int off = 16; off > 0; off >>= 1) m = fmaxf(m, __shfl_xor(m, off));
        float s = active ? (expf(vx - m) + expf(vy - m)) : 0.0f;
#pragma unroll
        for (int off = 16; off > 0; off >>= 1) s += __shfl_xor(s, off);
        float ls = logf(s);
        if (h == 0 && active) {
            float2 o2 = {vx - m - ls, vy - m - ls};
            *(float2*)&out[(size_t)c * O + 2 * j] = o2;
        }
    }
}

extern "C" void kernel_launch(void* const* d_in, const int* in_sizes, int n_in,
                              void* d_out, int out_size, void* d_ws, size_t ws_size,
                              hipStream_t stream) {
    const float* x    = (const float*)d_in[0];
    const int*   ei   = (const int*)  d_in[1];
    const float* sig1 = (const float*)d_in[2];
    const float* W1   = (const float*)d_in[3];
    const float* b1   = (const float*)d_in[4];
    const float* sig2 = (const float*)d_in[5];
    const float* W2   = (const float*)d_in[6];
    const float* b2   = (const float*)d_in[7];
    float* out = (float*)d_out;

    const int N = in_sizes[0] / F1;
    const int E = in_sizes[1] / 2;
    const int* row = ei;
    const int* col = ei + E;

    char* w = (char*)d_ws;
    auto alloc = [&](size_t bytes) { void* q = w; w += (bytes + 255) & ~255ull; return q; };
    int*   cntO    = (int*)  alloc((size_t)2 * N * 4);   // cntO,cntI adjacent (one memset, one scan)
    int*   cntI    = cntO + N;
    int*   rowptrO = (int*)  alloc((size_t)(N + 1) * 4);
    int*   rowptrI = (int*)  alloc((size_t)(N + 1) * 4);
    int*   adjO    = (int*)  alloc((size_t)E * 4);
    int*   adjI    = (int*)  alloc((size_t)E * 4);
    float* dis     = (float*)alloc((size_t)N * 4);
    float* isg1    = (float*)alloc(F1 * 4);
    float* isg2    = (float*)alloc(H * 4);
    int*   bsum    = (int*)  alloc(1024 * 4);
    float* bufXW   = (float*)alloc((size_t)N * H * 4);   // xw1
    float* bufH    = (float*)alloc((size_t)N * H * 4);   // h1
    float* bufXW2  = (float*)alloc((size_t)N * NC * 4);  // xw2

    const int B = 256;
    const int chunk = (N + NXCD - 1) / NXCD;
    const int WPP = 1024;                                 // work blocks per partition
    const int stride8 = WPP * B;
    dim3 g8(NXCD * WPP);
    const int M = 2 * N;
    const int nb = (M + SCAN_EPB - 1) / SCAN_EPB;        // must be <=1024

    // ---- graph build ----
    hipMemsetAsync(cntO, 0, (size_t)2 * N * 4, stream);
    isg_kernel<<<1, 128, 0, stream>>>(sig1, isg1, sig2, isg2);
    count8_kernel<<<g8, B, 0, stream>>>(row, col, cntO, cntI, E, chunk, stride8);
    scan_partial_kernel<<<nb, SCAN_TPB, 0, stream>>>(cntO, bsum, M);
    scan_offsets_kernel<<<1, 1024, 0, stream>>>(bsum, nb, rowptrO, rowptrI, N, E);
    scan_final_kernel<<<nb, SCAN_TPB, 0, stream>>>(cntO, cntI, bsum, rowptrO, rowptrI, dis, N, E);
    build8_kernel<<<g8, B, 0, stream>>>(row, col, cntO, cntI, adjO, adjI, E, chunk, stride8);

    // ---- layer 1 ----
    fused_mask_gemm_kernel<F1, H, 8><<<(N + 7) / 8, 512, 0, stream>>>(rowptrO, adjO, dis, x, isg1, W1, bufXW, N);
    agg_gather_kernel<H, 0><<<(N + 3) / 4, B, 0, stream>>>(rowptrI, adjI, dis, bufXW, b1, bufH, N);

    // ---- layer 2 ----
    fused_mask_gemm_kernel<H, NC, 8><<<(N + 7) / 8, 512, 0, stream>>>(rowptrO, adjO, dis, bufH, isg2, W2, bufXW2, N);
    agg_gather_kernel<NC, 1><<<(N + 3) / 4, B, 0, stream>>>(rowptrI, adjI, dis, bufXW2, b2, out, N);
}

// Round 6
// 672.487 us; speedup vs baseline: 2.8939x; 1.0686x over previous
//
#include <hip/hip_runtime.h>
#include <cmath>

constexpr int F1 = 128;  // input features
constexpr int H  = 64;   // hidden
constexpr int NC = 40;   // classes
constexpr int NXCD = 8;

constexpr int SCAN_TPB = 256;
constexpr int SCAN_IPT = 8;
constexpr int SCAN_EPB = SCAN_TPB * SCAN_IPT;  // 2048 elements per block

// ---- bf16 helpers (RNE pack, cheap unpack) ----
__device__ inline unsigned short f2bf(float f) {
    union { float f; unsigned u; } v; v.f = f;
    unsigned r = (v.u + 0x7FFFu + ((v.u >> 16) & 1u)) >> 16;
    return (unsigned short)r;
}
__device__ inline float bflo(unsigned p) {  // low bf16 of packed pair
    union { float f; unsigned u; } v; v.u = p << 16; return v.f;
}
__device__ inline float bfhi(unsigned p) {  // high bf16 of packed pair
    union { float f; unsigned u; } v; v.u = p & 0xFFFF0000u; return v.f;
}

// ---- inverse sigmas ----
__global__ void isg_kernel(const float* __restrict__ s1, float* __restrict__ i1,
                           const float* __restrict__ s2, float* __restrict__ i2) {
    int i = threadIdx.x;
    if (i < F1) i1[i] = 1.0f / s1[i];
    if (i < H)  i2[i] = 1.0f / s2[i];
}

// ---- u = bf16(x * isg), 8 features per thread ----
__global__ void prep_u_kernel(const float* __restrict__ x, const float* __restrict__ isg,
                              unsigned short* __restrict__ u, size_t n8, int F) {
    size_t idx = (size_t)blockIdx.x * blockDim.x + threadIdx.x;
    if (idx >= n8) return;
    size_t base = idx * 8;
    int fk = (int)(base % (size_t)F);
    float4 a0 = *(const float4*)&x[base];
    float4 a1 = *(const float4*)&x[base + 4];
    float4 s0 = *(const float4*)&isg[fk];
    float4 s1 = *(const float4*)&isg[fk + 4];
    uint4 p;
    p.x = (unsigned)f2bf(a0.x * s0.x) | ((unsigned)f2bf(a0.y * s0.y) << 16);
    p.y = (unsigned)f2bf(a0.z * s0.z) | ((unsigned)f2bf(a0.w * s0.w) << 16);
    p.z = (unsigned)f2bf(a1.x * s1.x) | ((unsigned)f2bf(a1.y * s1.y) << 16);
    p.w = (unsigned)f2bf(a1.z * s1.z) | ((unsigned)f2bf(a1.w * s1.w) << 16);
    *(uint4*)&u[base] = p;
}

// ---- XCD-partitioned degree histogram ----
__global__ void count8_kernel(const int* __restrict__ row, const int* __restrict__ col,
                              int* __restrict__ cntO, int* __restrict__ cntI,
                              int E, int chunk, int stride) {
    int p = blockIdx.x & (NXCD - 1);
    int gid = blockIdx.x >> 3;
    unsigned lo = (unsigned)(p * chunk);
    for (int e = gid * blockDim.x + threadIdx.x; e < E; e += stride) {
        int r = row[e], c = col[e];
        if ((unsigned)r - lo < (unsigned)chunk) atomicAdd(&cntO[r], 1);
        if ((unsigned)c - lo < (unsigned)chunk) atomicAdd(&cntI[c], 1);
    }
}

// ---- multi-block exclusive scan over cnt[0..M) (M = 2N: cntO|cntI contiguous) ----
__global__ void scan_partial_kernel(const int* __restrict__ cnt, int* __restrict__ bsum, int M) {
    __shared__ int red[SCAN_TPB];
    int t = threadIdx.x;
    int i0 = blockIdx.x * SCAN_EPB + t * SCAN_IPT;
    int s = 0;
#pragma unroll
    for (int k = 0; k < SCAN_IPT; ++k) {
        int i = i0 + k;
        if (i < M) s += cnt[i];
    }
    red[t] = s;
    __syncthreads();
    for (int off = SCAN_TPB / 2; off > 0; off >>= 1) {
        if (t < off) red[t] += red[t + off];
        __syncthreads();
    }
    if (t == 0) bsum[blockIdx.x] = red[0];
}

__global__ void scan_offsets_kernel(int* __restrict__ bsum, int nb,
                                    int* __restrict__ rowptrO, int* __restrict__ rowptrI,
                                    int N, int E) {
    __shared__ int sh[1024];
    int t = threadIdx.x;
    sh[t] = (t < nb) ? bsum[t] : 0;
    __syncthreads();
    for (int off = 1; off < 1024; off <<= 1) {
        int v = (t >= off) ? sh[t - off] : 0;
        __syncthreads();
        sh[t] += v;
        __syncthreads();
    }
    if (t < nb) bsum[t] = (t > 0) ? sh[t - 1] : 0;  // exclusive block offsets
    if (t == 0) { rowptrO[N] = E; rowptrI[N] = E; }
}

__global__ void scan_final_kernel(int* __restrict__ cntO, int* __restrict__ cntI,
                                  const int* __restrict__ bsum,
                                  int* __restrict__ rowptrO, int* __restrict__ rowptrI,
                                  float* __restrict__ dis, int N, int E) {
    __shared__ int sh[SCAN_TPB];
    int t = threadIdx.x;
    int M = 2 * N;
    const int* cnt = cntO;  // cntI == cntO + N (contiguous)
    int i0 = blockIdx.x * SCAN_EPB + t * SCAN_IPT;
    int cv[SCAN_IPT], pre[SCAN_IPT];
    int run = 0;
#pragma unroll
    for (int k = 0; k < SCAN_IPT; ++k) {
        int i = i0 + k;
        cv[k] = (i < M) ? cnt[i] : 0;
        pre[k] = run;
        run += cv[k];
    }
    sh[t] = run;
    __syncthreads();
    for (int off = 1; off < SCAN_TPB; off <<= 1) {
        int v = (t >= off) ? sh[t - off] : 0;
        __syncthreads();
        sh[t] += v;
        __syncthreads();
    }
    int toff = ((t > 0) ? sh[t - 1] : 0) + bsum[blockIdx.x];
#pragma unroll
    for (int k = 0; k < SCAN_IPT; ++k) {
        int i = i0 + k;
        if (i < M) {
            int val = toff + pre[k];
            if (i < N) {
                rowptrO[i] = val;
                cntO[i] = val;                         // cursor
                dis[i] = rsqrtf((float)(cv[k] + 1));   // deg includes self-loop
            } else {
                rowptrI[i - N] = val - E;
                cntI[i - N] = val - E;                 // cursor
            }
        }
    }
}

// ---- XCD-partitioned adjacency fill ----
__global__ void build8_kernel(const int* __restrict__ row, const int* __restrict__ col,
                              int* __restrict__ curO, int* __restrict__ curI,
                              int* __restrict__ adjO, int* __restrict__ adjI,
                              int E, int chunk, int stride) {
    int p = blockIdx.x & (NXCD - 1);
    int gid = blockIdx.x >> 3;
    unsigned lo = (unsigned)(p * chunk);
    for (int e = gid * blockDim.x + threadIdx.x; e < E; e += stride) {
        int r = row[e], c = col[e];
        if ((unsigned)r - lo < (unsigned)chunk) adjO[atomicAdd(&curO[r], 1)] = c;
        if ((unsigned)c - lo < (unsigned)chunk) adjI[atomicAdd(&curI[c], 1)] = r;
    }
}

// ---- fused: per-wave mask gather (bf16 u rows) + apply -> LDS X tile -> dense GEMM ----
// u = bf16(x*isg). mask term: nrm*(u_c - u_r)^2. Gather 16B/lane (8 bf16), G=F/8 lanes/row,
// NPI=64/G neighbors per wave-iteration.
template<int F, int O, int R>
__global__ void fused_mask_gemm_kernel(const int* __restrict__ rowptr, const int* __restrict__ adj,
                                       const float* __restrict__ dis, const float* __restrict__ x,
                                       const unsigned short* __restrict__ u,
                                       const float* __restrict__ W,
                                       float* __restrict__ Y, int N) {
    constexpr int NT = R * 64;
    constexpr int G = F / 8;        // lanes covering one row (8 bf16 = 16B each)
    constexpr int NPI = 64 / G;     // neighbors per wave-iteration
    __shared__ __align__(16) float Ws[F * O];
    __shared__ __align__(16) float Xs[R][F];
    int tid = threadIdx.x;
    for (int i = tid; i < F * O; i += NT) Ws[i] = W[i];

    int w = tid >> 6, lane = tid & 63;
    int h = lane / G;               // neighbor slot within iteration
    int j = lane % G;               // 8-feature chunk index within row
    int r = blockIdx.x * R + w;
    if (r < N) {
        int beg = rowptr[r], end = rowptr[r + 1];
        float dr = dis[r];
        float inv_deg = 1.0f / (float)(end - beg + 1);
        float xr[8], ur[8], acc[8];
        {
            float4 a0 = *(const float4*)&x[(size_t)r * F + 8 * j];
            float4 a1 = *(const float4*)&x[(size_t)r * F + 8 * j + 4];
            xr[0] = a0.x; xr[1] = a0.y; xr[2] = a0.z; xr[3] = a0.w;
            xr[4] = a1.x; xr[5] = a1.y; xr[6] = a1.z; xr[7] = a1.w;
            uint4 rr = *(const uint4*)&u[(size_t)r * F + 8 * j];
            ur[0] = bflo(rr.x); ur[1] = bfhi(rr.x);
            ur[2] = bflo(rr.y); ur[3] = bfhi(rr.y);
            ur[4] = bflo(rr.z); ur[5] = bfhi(rr.z);
            ur[6] = bflo(rr.w); ur[7] = bfhi(rr.w);
        }
#pragma unroll
        for (int k = 0; k < 8; ++k) acc[k] = 0.0f;
        for (int base = beg; base < end; base += 64) {
            int nn = min(64, end - base);
            int cl = 0; float dl = 0.0f;
            if (base + lane < end) { cl = adj[base + lane]; dl = dis[cl]; }
            for (int t = 0; t < nn; t += NPI) {
                int i = t + h;
                bool valid = i < nn;
                int ii = valid ? i : 0;
                int c = __shfl(cl, ii);
                float nrm = valid ? dr * __shfl(dl, ii) : 0.0f;
                uint4 raw = *(const uint4*)&u[(size_t)c * F + 8 * j];
                float uc[8];
                uc[0] = bflo(raw.x); uc[1] = bfhi(raw.x);
                uc[2] = bflo(raw.y); uc[3] = bfhi(raw.y);
                uc[4] = bflo(raw.z); uc[5] = bfhi(raw.z);
                uc[6] = bflo(raw.w); uc[7] = bfhi(raw.w);
#pragma unroll
                for (int k = 0; k < 8; ++k) {
                    float d = uc[k] - ur[k];
                    acc[k] = fmaf(nrm * d, d, acc[k]);
                }
            }
        }
#pragma unroll
        for (int off = G; off < 64; off <<= 1) {
#pragma unroll
            for (int k = 0; k < 8; ++k) acc[k] += __shfl_xor(acc[k], off);
        }
        if (h == 0) {
            float xm[8];
#pragma unroll
            for (int k = 0; k < 8; ++k) xm[k] = xr[k] * expf(-acc[k] * inv_deg);
            *(float4*)&Xs[w][8 * j]     = make_float4(xm[0], xm[1], xm[2], xm[3]);
            *(float4*)&Xs[w][8 * j + 4] = make_float4(xm[4], xm[5], xm[6], xm[7]);
        }
    } else {
        if (h == 0) {
            *(float4*)&Xs[w][8 * j]     = make_float4(0.f, 0.f, 0.f, 0.f);
            *(float4*)&Xs[w][8 * j + 4] = make_float4(0.f, 0.f, 0.f, 0.f);
        }
    }
    __syncthreads();

    int row0 = blockIdx.x * R;
    for (int idx = tid; idx < R * O; idx += NT) {
        int rr = idx / O, o = idx % O;
        if (row0 + rr < N) {
            float acc = 0.0f;
#pragma unroll
            for (int f = 0; f < F; ++f) acc = fmaf(Xs[rr][f], Ws[f * O + o], acc);
            Y[(size_t)(row0 + rr) * O + o] = acc;
        }
    }
}

// ---- aggregation gather: out[c] = sum_in dis[r]*dis[c]*xw[r] + dis[c]^2*xw[c], + epilogue
// float4 loads, 16 lanes/row, 4 neighbors per iteration.
// MODE 0: bias+relu, and writes u2 = bf16(h*isg2) for layer-2 mask gathers.
// MODE 1: bias+log_softmax over O lanes.
template<int O, int MODE>
__global__ void agg_gather_kernel(const int* __restrict__ rowptr, const int* __restrict__ adj,
                                  const float* __restrict__ dis, const float* __restrict__ xw,
                                  const float* __restrict__ bias, float* __restrict__ out,
                                  unsigned short* __restrict__ u2, const float* __restrict__ isg2,
                                  int N) {
    int c = blockIdx.x * (blockDim.x >> 6) + (threadIdx.x >> 6);
    if (c >= N) return;
    int lane = threadIdx.x & 63;
    int j = lane & 15, h = lane >> 4;   // 4 neighbor slots x 16 lanes
    bool active = (4 * j < O);
    int beg = rowptr[c], end = rowptr[c + 1];
    float dc = dis[c];
    float4 a = {0.f, 0.f, 0.f, 0.f};
    // self-loop term: ONLY slot h==0 (slots combined by shfl_xor(16)+(32) below)
    if (h == 0 && active) {
        float4 v = *(const float4*)&xw[(size_t)c * O + 4 * j];
        a.x = dc * dc * v.x; a.y = dc * dc * v.y;
        a.z = dc * dc * v.z; a.w = dc * dc * v.w;
    }
    for (int base = beg; base < end; base += 64) {
        int nn = min(64, end - base);
        int rl = 0; float dl = 0.0f;
        if (base + lane < end) { rl = adj[base + lane]; dl = dis[rl]; }
        for (int t = 0; t < nn; t += 4) {
            int i = t + h;
            bool valid = i < nn;
            int ii = valid ? i : 0;
            int rr = __shfl(rl, ii);
            float nrm = valid ? dc * __shfl(dl, ii) : 0.0f;
            if (active) {
                float4 v = *(const float4*)&xw[(size_t)rr * O + 4 * j];
                a.x = fmaf(nrm, v.x, a.x);
                a.y = fmaf(nrm, v.y, a.y);
                a.z = fmaf(nrm, v.z, a.z);
                a.w = fmaf(nrm, v.w, a.w);
            }
        }
    }
    a.x += __shfl_xor(a.x, 16); a.x += __shfl_xor(a.x, 32);
    a.y += __shfl_xor(a.y, 16); a.y += __shfl_xor(a.y, 32);
    a.z += __shfl_xor(a.z, 16); a.z += __shfl_xor(a.z, 32);
    a.w += __shfl_xor(a.w, 16); a.w += __shfl_xor(a.w, 32);
    if (MODE == 0) {
        if (h == 0 && active) {
            float4 bb = *(const float4*)&bias[4 * j];
            float4 o4;
            o4.x = fmaxf(a.x + bb.x, 0.0f);
            o4.y = fmaxf(a.y + bb.y, 0.0f);
            o4.z = fmaxf(a.z + bb.z, 0.0f);
            o4.w = fmaxf(a.w + bb.w, 0.0f);
            *(float4*)&out[(size_t)c * O + 4 * j] = o4;
            float4 s4 = *(const float4*)&isg2[4 * j];
            uint2 p;
            p.x = (unsigned)f2bf(o4.x * s4.x) | ((unsigned)f2bf(o4.y * s4.y) << 16);
            p.y = (unsigned)f2bf(o4.z * s4.z) | ((unsigned)f2bf(o4.w * s4.w) << 16);
            *(uint2*)&u2[(size_t)c * O + 4 * j] = p;
        }
    } else {
        float4 v = {-INFINITY, -INFINITY, -INFINITY, -INFINITY};
        if (active) {
            float4 bb = *(const float4*)&bias[4 * j];
            v.x = a.x + bb.x; v.y = a.y + bb.y; v.z = a.z + bb.z; v.w = a.w + bb.w;
        }
        float m = fmaxf(fmaxf(v.x, v.y), fmaxf(v.z, v.w));
#pragma unroll
        for (int off = 8; off > 0; off >>= 1) m = fmaxf(m, __shfl_xor(m, off));
        float s = active ? (expf(v.x - m) + expf(v.y - m) + expf(v.z - m) + expf(v.w - m)) : 0.0f;
#pragma unroll
        for (int off = 8; off > 0; off >>= 1) s += __shfl_xor(s, off);
        float mls = m + logf(s);
        if (h == 0 && active) {
            float4 o4 = {v.x - mls, v.y - mls, v.z - mls, v.w - mls};
            *(float4*)&out[(size_t)c * O + 4 * j] = o4;
        }
    }
}

extern "C" void kernel_launch(void* const* d_in, const int* in_sizes, int n_in,
                              void* d_out, int out_size, void* d_ws, size_t ws_size,
                              hipStream_t stream) {
    const float* x    = (const float*)d_in[0];
    const int*   ei   = (const int*)  d_in[1];
    const float* sig1 = (const float*)d_in[2];
    const float* W1   = (const float*)d_in[3];
    const float* b1   = (const float*)d_in[4];
    const float* sig2 = (const float*)d_in[5];
    const float* W2   = (const float*)d_in[6];
    const float* b2   = (const float*)d_in[7];
    float* out = (float*)d_out;

    const int N = in_sizes[0] / F1;
    const int E = in_sizes[1] / 2;
    const int* row = ei;
    const int* col = ei + E;

    char* w = (char*)d_ws;
    auto alloc = [&](size_t bytes) { void* q = w; w += (bytes + 255) & ~255ull; return q; };
    int*   cntO    = (int*)  alloc((size_t)2 * N * 4);
    int*   cntI    = cntO + N;
    int*   rowptrO = (int*)  alloc((size_t)(N + 1) * 4);
    int*   rowptrI = (int*)  alloc((size_t)(N + 1) * 4);
    int*   adjO    = (int*)  alloc((size_t)E * 4);
    int*   adjI    = (int*)  alloc((size_t)E * 4);
    float* dis     = (float*)alloc((size_t)N * 4);
    float* isg1    = (float*)alloc(F1 * 4);
    float* isg2    = (float*)alloc(H * 4);
    int*   bsum    = (int*)  alloc(1024 * 4);
    unsigned short* u1 = (unsigned short*)alloc((size_t)N * F1 * 2);  // bf16(x*isg1); dead after fused1
    unsigned short* u2 = (unsigned short*)alloc((size_t)N * H * 2);   // bf16(h1*isg2)
    float* bufXW   = (float*)alloc((size_t)N * H * 4);   // xw1
    float* bufH    = (float*)alloc((size_t)N * H * 4);   // h1
    float* bufXW2  = (float*)u1;                         // xw2 aliases u1 (u1 dead before fused2 writes)

    const int B = 256;
    const int chunk = (N + NXCD - 1) / NXCD;
    const int WPP = 1024;
    const int stride8 = WPP * B;
    dim3 g8(NXCD * WPP);
    const int M = 2 * N;
    const int nb = (M + SCAN_EPB - 1) / SCAN_EPB;        // must be <=1024

    // ---- graph build + u1 prep ----
    hipMemsetAsync(cntO, 0, (size_t)2 * N * 4, stream);
    isg_kernel<<<1, 128, 0, stream>>>(sig1, isg1, sig2, isg2);
    prep_u_kernel<<<(int)(((size_t)N * F1 / 8 + B - 1) / B), B, 0, stream>>>(x, isg1, u1, (size_t)N * F1 / 8, F1);
    count8_kernel<<<g8, B, 0, stream>>>(row, col, cntO, cntI, E, chunk, stride8);
    scan_partial_kernel<<<nb, SCAN_TPB, 0, stream>>>(cntO, bsum, M);
    scan_offsets_kernel<<<1, 1024, 0, stream>>>(bsum, nb, rowptrO, rowptrI, N, E);
    scan_final_kernel<<<nb, SCAN_TPB, 0, stream>>>(cntO, cntI, bsum, rowptrO, rowptrI, dis, N, E);
    build8_kernel<<<g8, B, 0, stream>>>(row, col, cntO, cntI, adjO, adjI, E, chunk, stride8);

    // ---- layer 1 ----
    fused_mask_gemm_kernel<F1, H, 8><<<(N + 7) / 8, 512, 0, stream>>>(rowptrO, adjO, dis, x, u1, W1, bufXW, N);
    agg_gather_kernel<H, 0><<<(N + 3) / 4, B, 0, stream>>>(rowptrI, adjI, dis, bufXW, b1, bufH, u2, isg2, N);

    // ---- layer 2 ----
    fused_mask_gemm_kernel<H, NC, 8><<<(N + 7) / 8, 512, 0, stream>>>(rowptrO, adjO, dis, bufH, u2, W2, bufXW2, N);
    agg_gather_kernel<NC, 1><<<(N + 3) / 4, B, 0, stream>>>(rowptrI, adjI, dis, bufXW2, b2, out, nullptr, nullptr, N);
}